// Round 13
// baseline (14134.322 us; speedup 1.0000x reference)
//
#include <hip/hip_runtime.h>
#include <hip/hip_bf16.h>

typedef __hip_bfloat16 bf16;
typedef __attribute__((ext_vector_type(8))) short bf16x8;
typedef __attribute__((ext_vector_type(4))) float f32x4;

__device__ __forceinline__ float bf2f(bf16 v) { return __bfloat162float(v); }
__device__ __forceinline__ unsigned short f2bfu(float f) {
    bf16 h = __float2bfloat16(f);
    return __builtin_bit_cast(unsigned short, h);
}

__device__ __forceinline__ void gload16(const void* g, void* lds) {
    __builtin_amdgcn_global_load_lds(
        (const __attribute__((address_space(1))) unsigned int*)g,
        (__attribute__((address_space(3))) unsigned int*)lds, 16, 0, 0);
}

// cheap exact-enough GELU: tanh form, max |err| vs erf-GELU ~5e-4
__device__ __forceinline__ float gelu_f(float x) {
    float u = 0.7978845608f * (x + 0.044715f * x * x * x);
    float e = __expf(-2.0f * fabsf(u));
    float th = (1.f - e) / (1.f + e);
    th = u < 0.f ? -th : th;
    return 0.5f * x * (1.f + th);
}

// ---------------------------------------------------------------- conv1 + ReLU + BN1
__global__ __launch_bounds__(256)
void conv1_kernel(const float* __restrict__ x, const float* __restrict__ w,
                  const float* __restrict__ bias,
                  const float* __restrict__ g, const float* __restrict__ b,
                  const float* __restrict__ m, const float* __restrict__ v,
                  bf16* __restrict__ h1) {
    int bo = blockIdx.x;
    int bb = bo >> 8, o = bo & 255;
    int l = threadIdx.x;
    if (l >= 200) return;
    const float* wo = w + o * 60;
    const float* xb = x + bb * 12000;
    float acc = bias[o];
#pragma unroll
    for (int i = 0; i < 12; i++)
#pragma unroll
        for (int t = 0; t < 5; t++)
            acc = fmaf(xb[i * 1000 + 5 * l + t], wo[i * 5 + t], acc);
    acc = fmaxf(acc, 0.f);
    float sc = g[o] * rsqrtf(v[o] + 1e-5f);
    acc = (acc - m[o]) * sc + b[o];
    h1[bo * 200 + l] = __float2bfloat16(acc);
}

// ---------------------------------------------------------------- im2col for conv2
__global__ __launch_bounds__(256)
void im2col_kernel(const bf16* __restrict__ h1, bf16* __restrict__ A2) {
    int idx = blockIdx.x * 256 + threadIdx.x;
    int row = idx / 1280, c = idx - row * 1280;
    int bb = row / 196, l = row - bb * 196;
    int i = c / 5, t = c - i * 5;
    A2[idx] = h1[(bb * 256 + i) * 200 + l + t];
}

// ---------------------------------------------------------------- cls token row
__global__ __launch_bounds__(256)
void add_cls_pos(const float* __restrict__ cls, const float* __restrict__ pos,
                 float* __restrict__ tok) {
    int idx = blockIdx.x * 256 + threadIdx.x;   // < 64*768
    int bb = idx / 768, d = idx - bb * 768;
    tok[(size_t)bb * 197 * 768 + d] = cls[d] + pos[d];
}

// ---------------------------------------------------------------- fp32 -> bf16 elementwise
__global__ __launch_bounds__(256)
void cvt_kernel(const float* __restrict__ in, bf16* __restrict__ out, int n) {
    int idx = blockIdx.x * 256 + threadIdx.x;
    if (idx < n) out[idx] = __float2bfloat16(in[idx]);
}

// ---------------------------------------------------------------- per-layer weight transpose+convert
__global__ __launch_bounds__(256)
void wtrans_layer(const float* __restrict__ qkvw, const float* __restrict__ projw,
                  const float* __restrict__ fc1w, const float* __restrict__ fc2w,
                  bf16* __restrict__ qkvT, bf16* __restrict__ projT,
                  bf16* __restrict__ fc1T, bf16* __restrict__ fc2T) {
    __shared__ float tile[32][33];
    int blk = blockIdx.x;
    const float* in; bf16* out; int Kd, Nd, t0;
    if (blk < 1728)      { in = qkvw; out = qkvT; Kd = 768;  Nd = 2304; t0 = blk; }
    else if (blk < 2304) { in = projw; out = projT; Kd = 768;  Nd = 768;  t0 = blk - 1728; }
    else if (blk < 4608) { in = fc1w; out = fc1T; Kd = 768;  Nd = 3072; t0 = blk - 2304; }
    else                 { in = fc2w; out = fc2T; Kd = 3072; Nd = 768;  t0 = blk - 4608; }
    int ntiles = Nd >> 5;
    int kt = t0 / ntiles, nt = t0 - kt * ntiles;
    int k0 = kt * 32, n0 = nt * 32;
    int tx = threadIdx.x & 31, ty = threadIdx.x >> 5;   // ty 0..7
#pragma unroll
    for (int j = 0; j < 4; j++)
        tile[ty + 8 * j][tx] = in[(size_t)(k0 + ty + 8 * j) * Nd + n0 + tx];
    __syncthreads();
#pragma unroll
    for (int j = 0; j < 4; j++)
        out[(size_t)(n0 + ty + 8 * j) * Kd + k0 + tx] = __float2bfloat16(tile[tx][ty + 8 * j]);
}

// ---------------------------------------------------------------- generic transpose+convert (head weights)
__global__ __launch_bounds__(256)
void wtrans2(const float* __restrict__ in, bf16* __restrict__ out, int Kd, int Nd) {
    __shared__ float tile[32][33];
    int ntiles = Nd >> 5;
    int kt = blockIdx.x / ntiles, nt = blockIdx.x - kt * ntiles;
    int k0 = kt * 32, n0 = nt * 32;
    int tx = threadIdx.x & 31, ty = threadIdx.x >> 5;
#pragma unroll
    for (int j = 0; j < 4; j++)
        tile[ty + 8 * j][tx] = in[(size_t)(k0 + ty + 8 * j) * Nd + n0 + tx];
    __syncthreads();
#pragma unroll
    for (int j = 0; j < 4; j++)
        out[(size_t)(n0 + ty + 8 * j) * Kd + k0 + tx] = __float2bfloat16(tile[tx][ty + 8 * j]);
}

// ---------------------------------------------------------------- LayerNorm (wave per row) -> bf16
__global__ __launch_bounds__(256)
void ln_kernel(const float* __restrict__ x, bf16* __restrict__ y,
               const float* __restrict__ g, const float* __restrict__ b,
               int nrows, int xstride) {
    int row = blockIdx.x * 4 + (threadIdx.x >> 6);
    if (row >= nrows) return;
    int l = threadIdx.x & 63;
    const float* xr = x + (size_t)row * xstride;
    float4 v0 = *(const float4*)(xr + l * 4);
    float4 v1 = *(const float4*)(xr + 256 + l * 4);
    float4 v2 = *(const float4*)(xr + 512 + l * 4);
    float s1 = 0.f, s2 = 0.f;
    {
        float e;
        e = v0.x; s1 += e; s2 += e * e;  e = v0.y; s1 += e; s2 += e * e;
        e = v0.z; s1 += e; s2 += e * e;  e = v0.w; s1 += e; s2 += e * e;
        e = v1.x; s1 += e; s2 += e * e;  e = v1.y; s1 += e; s2 += e * e;
        e = v1.z; s1 += e; s2 += e * e;  e = v1.w; s1 += e; s2 += e * e;
        e = v2.x; s1 += e; s2 += e * e;  e = v2.y; s1 += e; s2 += e * e;
        e = v2.z; s1 += e; s2 += e * e;  e = v2.w; s1 += e; s2 += e * e;
    }
#pragma unroll
    for (int off = 1; off < 64; off <<= 1) {
        s1 += __shfl_xor(s1, off);
        s2 += __shfl_xor(s2, off);
    }
    float mu = s1 * (1.f / 768.f);
    float rs = rsqrtf(s2 * (1.f / 768.f) - mu * mu + 1e-6f);
    bf16* yr = y + (size_t)row * 768;
#pragma unroll
    for (int sgi = 0; sgi < 3; sgi++) {
        float4 vv = sgi == 0 ? v0 : (sgi == 1 ? v1 : v2);
        float4 gg = *(const float4*)(g + sgi * 256 + l * 4);
        float4 bb = *(const float4*)(b + sgi * 256 + l * 4);
        ushort4 o;
        o.x = f2bfu((vv.x - mu) * rs * gg.x + bb.x);
        o.y = f2bfu((vv.y - mu) * rs * gg.y + bb.y);
        o.z = f2bfu((vv.z - mu) * rs * gg.z + bb.z);
        o.w = f2bfu((vv.w - mu) * rs * gg.w + bb.w);
        *(ushort4*)(yr + sgi * 256 + l * 4) = o;
    }
}

// ---------------------------------------------------------------- gemm2: 128x128, BK=64, 4 waves,
// single-buffer static LDS (R3/R6 proven) + XCD-chunked bijective swizzle (m204).
enum { E_BF16 = 0, E_RESID = 1, E_GELU = 2, E_CONV2 = 3, E_HEAD1 = 4, E_HEAD2 = 5 };

template<int EPI>
__global__ __launch_bounds__(256)
void gemm2(const bf16* __restrict__ A, const bf16* __restrict__ Bt,
           int M, int N, int K,
           const float* __restrict__ bias,
           bf16* __restrict__ Co, float* __restrict__ tok,
           const float* __restrict__ bng, const float* __restrict__ bnb,
           const float* __restrict__ bnm, const float* __restrict__ bnv,
           const float* __restrict__ pos) {
    __shared__ bf16 As[128 * 64];
    __shared__ bf16 Bs[128 * 64];
    const int t = threadIdx.x;
    const int l = t & 63, w = t >> 6;
    const int wm = (w >> 1) * 64, wn = (w & 1) * 64;

    const int gx = gridDim.x;
    const int nwg = gx * gridDim.y;
    const int d = blockIdx.y * gx + blockIdx.x;
    const int q = nwg >> 3, r = nwg & 7;
    const int xcd = d & 7, pos_ = d >> 3;
    const int lid = (xcd < r ? xcd * (q + 1) : r * (q + 1) + (xcd - r) * q) + pos_;
    const int row0 = (lid / gx) * 128, col0 = (lid % gx) * 128;

    const int lr = l & 15, kg = l >> 4;

    const int srow = w * 8 + (l >> 3);
    const int sc = ((l & 7) ^ (l >> 3)) * 8;
    const int dstoff = w * 1024 + l * 16;

    const f32x4 zero4 = {0.f, 0.f, 0.f, 0.f};
    f32x4 acc[4][4];
#pragma unroll
    for (int i = 0; i < 4; i++)
#pragma unroll
        for (int j = 0; j < 4; j++) acc[i][j] = zero4;

    for (int k0 = 0; k0 < K; k0 += 64) {
#pragma unroll
        for (int p = 0; p < 4; p++) {
            int rr = srow + p * 32;
            int gra = row0 + rr; if (gra >= M) gra = M - 1;
            gload16(A + (size_t)gra * K + k0 + sc, (char*)As + p * 4096 + dstoff);
            gload16(Bt + (size_t)(col0 + rr) * K + k0 + sc, (char*)Bs + p * 4096 + dstoff);
        }
        __syncthreads();
#pragma unroll
        for (int ks = 0; ks < 2; ks++) {
            bf16x8 af[4], bfv[4];
            const int cc = ((ks * 4 + kg) ^ (lr & 7)) * 16;
#pragma unroll
            for (int i = 0; i < 4; i++) {
                af[i]  = *(const bf16x8*)((const char*)As + (wm + i * 16 + lr) * 128 + cc);
                bfv[i] = *(const bf16x8*)((const char*)Bs + (wn + i * 16 + lr) * 128 + cc);
            }
#pragma unroll
            for (int i = 0; i < 4; i++)
#pragma unroll
                for (int j = 0; j < 4; j++)
                    acc[i][j] = __builtin_amdgcn_mfma_f32_16x16x32_bf16(af[i], bfv[j], acc[i][j], 0, 0, 0);
        }
        __syncthreads();
    }

    const int rbase = row0 + wm + (kg << 2);
#pragma unroll
    for (int i = 0; i < 4; i++) {
#pragma unroll
        for (int sr = 0; sr < 4; sr++) {
            int rr = rbase + i * 16 + sr;
            if (rr < M) {
#pragma unroll
                for (int j = 0; j < 4; j++) {
                    int c = col0 + wn + j * 16 + lr;
                    float vv = acc[i][j][sr];
                    if (EPI == E_BF16) {
                        Co[(size_t)rr * N + c] = __float2bfloat16(vv);
                    } else if (EPI == E_RESID) {
                        float* p = tok + (size_t)rr * N + c;
                        *p += vv + bias[c];
                    } else if (EPI == E_GELU) {
                        Co[(size_t)rr * N + c] = __float2bfloat16(gelu_f(vv + bias[c]));
                    } else if (EPI == E_CONV2) {
                        float xx = vv + bias[c];
                        xx = fmaxf(xx, 0.f);
                        float sc2 = bng[c] * rsqrtf(bnv[c] + 1e-5f);
                        xx = (xx - bnm[c]) * sc2 + bnb[c];
                        int bb = rr / 196, ll = rr - bb * 196;
                        xx += pos[(size_t)(1 + ll) * 768 + c];
                        tok[(size_t)(bb * 197 + 1 + ll) * 768 + c] = xx;
                    } else if (EPI == E_HEAD1) {
                        float sc2 = bng[c] * rsqrtf(bnv[c] + 1e-5f);
                        float xx = (vv - bnm[c]) * sc2 + bnb[c];
                        xx = fmaxf(xx, 0.f);
                        Co[(size_t)rr * N + c] = __float2bfloat16(xx);
                    } else {
                        float sc2 = bng[c] * rsqrtf(bnv[c] + 1e-5f);
                        tok[(size_t)rr * N + c] = (vv - bnm[c]) * sc2 + bnb[c];
                    }
                }
            }
        }
    }
}

// ---------------------------------------------------------------- gemm3: 256x256 tile, 8 waves, BK=32,
// 2-buffer double-buffered LDS (64 KB), R4-style schedule: stage(j+1) -> compute(j) -> vmcnt(0)+barrier.
// R8's verified conflict-free swizzle. __launch_bounds__(512,4): 4 waves/EU = 2 blocks/CU declared
// (R12's (512,2) declared only 1 block/CU and the occupancy gain never materialized).
#define G3_LDS 65536

template<int EPI>
__global__ __launch_bounds__(512, 4)
void gemm3(const bf16* __restrict__ A, const bf16* __restrict__ Bt,
           int M, int N, int K,
           const float* __restrict__ bias, bf16* __restrict__ Co) {
    extern __shared__ char smem[];   // 2 bufs x { A 16K | B 16K }
    const int t = threadIdx.x;
    const int l = t & 63, wid = t >> 6;
    const int wr = wid >> 2, wc = wid & 3;          // wave -> (row half, col quarter)
    const int lr = l & 15, kg = l >> 4;

    // XCD-chunked bijective swizzle (m204)
    const int gx = gridDim.x;
    const int nwg = gx * gridDim.y;
    const int d = blockIdx.y * gx + blockIdx.x;
    const int q = nwg >> 3, r = nwg & 7;
    const int xcd = d & 7, pp = d >> 3;
    const int lid = (xcd < r ? xcd * (q + 1) : r * (q + 1) + (xcd - r) * q) + pp;
    const int row0 = (lid / gx) * 256, col0 = (lid % gx) * 256;

    // staging: thread t covers rows (t>>2) and 128+(t>>2), phys chunk (t&3);
    // source logical chunk = (t&3) ^ ((row>>1)&3) = (t&3) ^ ((t>>3)&3)
    const int srow = t >> 2;                          // 0..127
    const int clog = ((t & 3) ^ ((t >> 3) & 3)) * 8;  // element offset of logical chunk
    int ga0 = row0 + srow;        if (ga0 >= M) ga0 = M - 1;
    int ga1 = row0 + 128 + srow;  if (ga1 >= M) ga1 = M - 1;
    const bf16* Ap0 = A + (size_t)ga0 * K + clog;
    const bf16* Ap1 = A + (size_t)ga1 * K + clog;
    const bf16* Bp0 = Bt + (size_t)(col0 + srow) * K + clog;
    const bf16* Bp1 = Bt + (size_t)(col0 + 128 + srow) * K + clog;
    const int dst = t * 16;

    const f32x4 zero4 = {0.f, 0.f, 0.f, 0.f};
    f32x4 acc[8][4];
#pragma unroll
    for (int i = 0; i < 8; i++)
#pragma unroll
        for (int n = 0; n < 4; n++) acc[i][n] = zero4;

    auto stage = [&](int j) {
        char* base = smem + (j & 1) * 32768 + dst;
        const int ke = j * 32;
        gload16(Ap0 + ke, base);
        gload16(Ap1 + ke, base + 8192);
        gload16(Bp0 + ke, base + 16384);
        gload16(Bp1 + ke, base + 16384 + 8192);
    };

    // read addressing: row R at byte R*64, phys chunk = kg ^ ((R>>1)&3); (R>>1)&3 == (lr>>1)&3
    const int ccA = ((kg ^ ((lr >> 1) & 3)) * 16);
    const int arow = (wr * 128 + lr) * 64 + ccA;       // + i*16*64
    const int brow = (wc * 64 + lr) * 64 + ccA;        // + n*16*64, +16384

    auto compute = [&](int j) {
        const char* ab = smem + (j & 1) * 32768;
        bf16x8 bfrag[4];
#pragma unroll
        for (int n = 0; n < 4; n++)
            bfrag[n] = *(const bf16x8*)(ab + 16384 + brow + n * 1024);
#pragma unroll
        for (int mh = 0; mh < 2; mh++) {
            bf16x8 af[4];
#pragma unroll
            for (int i2 = 0; i2 < 4; i2++)
                af[i2] = *(const bf16x8*)(ab + arow + (mh * 4 + i2) * 1024);
            __builtin_amdgcn_s_setprio(1);
#pragma unroll
            for (int i2 = 0; i2 < 4; i2++)
#pragma unroll
                for (int n = 0; n < 4; n++)
                    acc[mh * 4 + i2][n] = __builtin_amdgcn_mfma_f32_16x16x32_bf16(
                        af[i2], bfrag[n], acc[mh * 4 + i2][n], 0, 0, 0);
            __builtin_amdgcn_s_setprio(0);
        }
    };

    const int nt = K >> 5;
    stage(0);
    asm volatile("s_waitcnt vmcnt(0)" ::: "memory");
    __syncthreads();

    for (int j = 0; j < nt; ++j) {
        if (j + 1 < nt) stage(j + 1);      // -> buf (j+1)&1, disjoint from compute's buf j&1
        compute(j);
        asm volatile("s_waitcnt vmcnt(0)" ::: "memory");   // stage(j+1) landed
        __syncthreads();                   // all waves done reading buf j&1 -> safe to overwrite next iter
    }

    // epilogue: row = row0 + wr*128 + i*16 + kg*4 + sr; col = col0 + wc*64 + n*16 + lr
    float bs[4];
#pragma unroll
    for (int n = 0; n < 4; n++)
        bs[n] = (EPI == E_GELU) ? bias[col0 + wc * 64 + n * 16 + lr] : 0.f;
    const int rb = row0 + wr * 128 + kg * 4;
    const int cb = col0 + wc * 64 + lr;
#pragma unroll
    for (int i = 0; i < 8; i++) {
#pragma unroll
        for (int sr = 0; sr < 4; sr++) {
            int rr = rb + i * 16 + sr;
            if (rr < M) {
#pragma unroll
                for (int n = 0; n < 4; n++) {
                    float vv = acc[i][n][sr];
                    if (EPI == E_GELU) vv = gelu_f(vv + bs[n]);
                    Co[(size_t)rr * N + cb + n * 16] = __float2bfloat16(vv);
                }
            }
        }
    }
}

// ---------------------------------------------------------------- fused attention, 1 block per (b,h)
#define ATTN_LDS (208 * 72 * 2 + 64 * 232 * 2 + 4 * 16 * 232 * 2)

__global__ __launch_bounds__(256)
void attn_kernel(const bf16* __restrict__ qkv, bf16* __restrict__ o) {
    extern __shared__ char smem[];
    bf16* Ks = (bf16*)smem;          // [208][72]
    bf16* Vt = Ks + 208 * 72;        // [64][232]
    bf16* Pl = Vt + 64 * 232;        // [4][16][232]
    const int bh = blockIdx.x, bb = bh / 12, h = bh - bb * 12;
    const int t = threadIdx.x, w = t >> 6, l = t & 63;
    const int lr = l & 15, lk8 = (l >> 4) * 8;
    const size_t base = (size_t)bb * 197 * 2304 + (size_t)h * 64;

    for (int qi = t; qi < 197 * 16; qi += 256) {   // K rows
        int n = qi >> 4, d4 = (qi & 15) << 2;
        ushort4 kv = *(const ushort4*)(qkv + base + (size_t)n * 2304 + 768 + d4);
        *(ushort4*)&Ks[n * 72 + d4] = kv;
    }
    for (int qi = t; qi < 11 * 72; qi += 256) ((unsigned short*)Ks)[197 * 72 + qi] = 0;
    for (int qi = t; qi < 197 * 16; qi += 256) {   // V transposed
        int n = qi >> 4, d4 = (qi & 15) << 2;
        ushort4 vv = *(const ushort4*)(qkv + base + (size_t)n * 2304 + 1536 + d4);
        ((unsigned short*)Vt)[(d4 + 0) * 232 + n] = vv.x;
        ((unsigned short*)Vt)[(d4 + 1) * 232 + n] = vv.y;
        ((unsigned short*)Vt)[(d4 + 2) * 232 + n] = vv.z;
        ((unsigned short*)Vt)[(d4 + 3) * 232 + n] = vv.w;
    }
    for (int qi = t; qi < 64 * 35; qi += 256) {
        int d = qi / 35, c = 197 + (qi - d * 35);
        ((unsigned short*)Vt)[d * 232 + c] = 0;
    }
    __syncthreads();

    bf16* Pw = Pl + w * (16 * 232);
    const f32x4 zero4 = {0.f, 0.f, 0.f, 0.f};
    for (int qt = w; qt < 13; qt += 4) {
        int m0 = qt * 16;
        int qrow = m0 + lr; if (qrow > 196) qrow = 196;
        const bf16* qp = qkv + (size_t)(bb * 197 + qrow) * 2304 + h * 64 + lk8;
        bf16x8 a0 = *(const bf16x8*)qp;
        bf16x8 a1 = *(const bf16x8*)(qp + 32);
        f32x4 s[13];
#pragma unroll
        for (int kt = 0; kt < 13; kt++) {
            const bf16* kp = &Ks[(kt * 16 + lr) * 72 + lk8];
            bf16x8 b0 = *(const bf16x8*)kp;
            bf16x8 b1 = *(const bf16x8*)(kp + 32);
            f32x4 z = zero4;
            z = __builtin_amdgcn_mfma_f32_16x16x32_bf16(a0, b0, z, 0, 0, 0);
            z = __builtin_amdgcn_mfma_f32_16x16x32_bf16(a1, b1, z, 0, 0, 0);
            s[kt] = z;
        }
        float mx[4] = {-1e30f, -1e30f, -1e30f, -1e30f};
#pragma unroll
        for (int kt = 0; kt < 13; kt++) {
            bool valid = (kt < 12) || (lr <= 4);    // col = kt*16+lr <= 196
#pragma unroll
            for (int sr = 0; sr < 4; sr++) {
                float sv = s[kt][sr] * 0.125f;
                sv = valid ? sv : -1e30f;
                s[kt][sr] = sv;
                mx[sr] = fmaxf(mx[sr], sv);
            }
        }
#pragma unroll
        for (int off = 1; off < 16; off <<= 1)
#pragma unroll
            for (int sr = 0; sr < 4; sr++)
                mx[sr] = fmaxf(mx[sr], __shfl_xor(mx[sr], off));
        float sum[4] = {0.f, 0.f, 0.f, 0.f};
#pragma unroll
        for (int kt = 0; kt < 13; kt++)
#pragma unroll
            for (int sr = 0; sr < 4; sr++) {
                float p = __expf(s[kt][sr] - mx[sr]);
                s[kt][sr] = p;
                sum[sr] += p;
            }
#pragma unroll
        for (int off = 1; off < 16; off <<= 1)
#pragma unroll
            for (int sr = 0; sr < 4; sr++)
                sum[sr] += __shfl_xor(sum[sr], off);
        float inv[4];
#pragma unroll
        for (int sr = 0; sr < 4; sr++) inv[sr] = 1.f / sum[sr];
#pragma unroll
        for (int kt = 0; kt < 13; kt++)
#pragma unroll
            for (int sr = 0; sr < 4; sr++)
                ((unsigned short*)Pw)[((l >> 4) * 4 + sr) * 232 + kt * 16 + lr] =
                    f2bfu(s[kt][sr] * inv[sr]);
        for (int j = l; j < 256; j += 64) {        // zero P cols 208..223
            int rr = j >> 4, cc = 208 + (j & 15);
            ((unsigned short*)Pw)[rr * 232 + cc] = 0;
        }
        asm volatile("s_waitcnt lgkmcnt(0)" ::: "memory");
        f32x4 oa[4];
#pragma unroll
        for (int nf = 0; nf < 4; nf++) oa[nf] = zero4;
#pragma unroll
        for (int ks = 0; ks < 7; ks++) {
            const bf16* pp = &Pw[lr * 232 + ks * 32 + lk8];
            bf16x8 ap = *(const bf16x8*)pp;
#pragma unroll
            for (int nf = 0; nf < 4; nf++) {
                bf16x8 bv = *(const bf16x8*)&Vt[(nf * 16 + lr) * 232 + ks * 32 + lk8];
                oa[nf] = __builtin_amdgcn_mfma_f32_16x16x32_bf16(ap, bv, oa[nf], 0, 0, 0);
            }
        }
#pragma unroll
        for (int nf = 0; nf < 4; nf++)
#pragma unroll
            for (int sr = 0; sr < 4; sr++) {
                int orow = m0 + (l >> 4) * 4 + sr;
                if (orow <= 196)
                    o[(size_t)(bb * 197 + orow) * 768 + h * 64 + nf * 16 + lr] =
                        __float2bfloat16(oa[nf][sr]);
            }
    }
}

// ================================================================ host
extern "C" void kernel_launch(void* const* d_in, const int* in_sizes, int n_in,
                              void* d_out, int out_size, void* d_ws, size_t ws_size,
                              hipStream_t stream) {
    (void)in_sizes; (void)n_in; (void)out_size; (void)ws_size;
    const float* x        = (const float*)d_in[0];
    const float* conv1_w  = (const float*)d_in[1];
    const float* conv1_b  = (const float*)d_in[2];
    const float* bn1_g = (const float*)d_in[3],  *bn1_b = (const float*)d_in[4];
    const float* bn1_m = (const float*)d_in[5],  *bn1_v = (const float*)d_in[6];
    const float* conv2_w  = (const float*)d_in[7];
    const float* conv2_b  = (const float*)d_in[8];
    const float* bn2_g = (const float*)d_in[9],  *bn2_b = (const float*)d_in[10];
    const float* bn2_m = (const float*)d_in[11], *bn2_v = (const float*)d_in[12];
    const float* cls_tok  = (const float*)d_in[13];
    const float* pos      = (const float*)d_in[14];
    const float* ln1_g = (const float*)d_in[15], *ln1_b = (const float*)d_in[16];
    const float* qkv_w = (const float*)d_in[17];
    const float* proj_w = (const float*)d_in[18], *proj_b = (const float*)d_in[19];
    const float* ln2_g = (const float*)d_in[20], *ln2_b = (const float*)d_in[21];
    const float* fc1_w = (const float*)d_in[22], *fc1_b = (const float*)d_in[23];
    const float* fc2_w = (const float*)d_in[24], *fc2_b = (const float*)d_in[25];
    const float* norm_g = (const float*)d_in[26], *norm_b = (const float*)d_in[27];
    const float* p1_w = (const float*)d_in[28];
    const float* p1g = (const float*)d_in[29], *p1b = (const float*)d_in[30];
    const float* p1m = (const float*)d_in[31], *p1v = (const float*)d_in[32];
    const float* p2_w = (const float*)d_in[33];
    const float* p2g = (const float*)d_in[34], *p2b = (const float*)d_in[35];
    const float* p2m = (const float*)d_in[36], *p2v = (const float*)d_in[37];

    char* ws = (char*)d_ws;
    float* tok  = (float*)(ws + 0);                        // 38,731,776 B
    bf16* ybf   = (bf16*)(ws + 38731776);                  // 19,365,888 B (LN out / attn out)
    bf16* qkvb  = (bf16*)(ws + 58097664);                  // 58,097,664 B
    bf16* a1    = (bf16*)(ws + 116195328);                 // 77,463,552 B (GELU act)
    bf16* h1    = (bf16*)(ws + 116195328);                 // alias (prologue only)
    bf16* A2    = (bf16*)(ws + 116195328 + 8388608);       // alias (prologue only)
    bf16* clsb  = (bf16*)(ws + 193658880);                 // 98,304 B
    bf16* z1    = (bf16*)(ws + 193757184);                 // 98,304 B
    bf16* wtb   = (bf16*)(ws + 193953792);                 // 14,155,776 B (per-layer bf16 weights)
    bf16* qkvT = wtb;                                      // [2304][768]
    bf16* projT = wtb + 1769472;                           // [768][768]
    bf16* fc1T = wtb + 2359296;                            // [3072][768]
    bf16* fc2T = wtb + 4718592;                            // [768][3072]
    bf16* conv2T = wtb;                                    // prologue alias [768][1280]
    bf16* p1T = a1;                                        // epilogue alias [768][768]
    bf16* p2T = a1 + 768 * 768;                            // epilogue alias [512][768]

    (void)hipFuncSetAttribute((const void*)attn_kernel,
                              hipFuncAttributeMaxDynamicSharedMemorySize, ATTN_LDS);
    (void)hipFuncSetAttribute((const void*)gemm3<E_BF16>,
                              hipFuncAttributeMaxDynamicSharedMemorySize, G3_LDS);
    (void)hipFuncSetAttribute((const void*)gemm3<E_GELU>,
                              hipFuncAttributeMaxDynamicSharedMemorySize, G3_LDS);

    // ---- patch embed
    conv1_kernel<<<64 * 256, 256, 0, stream>>>(x, conv1_w, conv1_b, bn1_g, bn1_b, bn1_m, bn1_v, h1);
    im2col_kernel<<<(12544 * 1280) / 256, 256, 0, stream>>>(h1, A2);
    cvt_kernel<<<(768 * 1280 + 255) / 256, 256, 0, stream>>>(conv2_w, conv2T, 768 * 1280);
    gemm2<E_CONV2><<<dim3(6, 98), 256, 0, stream>>>(
        A2, conv2T, 12544, 768, 1280, conv2_b, nullptr, tok, bn2_g, bn2_b, bn2_m, bn2_v, pos);
    add_cls_pos<<<(64 * 768) / 256, 256, 0, stream>>>(cls_tok, pos, tok);

    const int MT = (12608 + 127) / 128;  // 99
    const int MT3 = (12608 + 255) / 256; // 50
    for (int i = 0; i < 12; i++) {
        wtrans_layer<<<6912, 256, 0, stream>>>(
            qkv_w + (size_t)i * 768 * 2304, proj_w + (size_t)i * 768 * 768,
            fc1_w + (size_t)i * 768 * 3072, fc2_w + (size_t)i * 3072 * 768,
            qkvT, projT, fc1T, fc2T);
        ln_kernel<<<12608 / 4, 256, 0, stream>>>(tok, ybf, ln1_g + i * 768, ln1_b + i * 768, 12608, 768);
        gemm3<E_BF16><<<dim3(9, MT3), 512, G3_LDS, stream>>>(
            ybf, qkvT, 12608, 2304, 768, nullptr, qkvb);
        attn_kernel<<<768, 256, ATTN_LDS, stream>>>(qkvb, ybf);
        gemm2<E_RESID><<<dim3(6, MT), 256, 0, stream>>>(
            ybf, projT, 12608, 768, 768,
            proj_b + i * 768, nullptr, tok, nullptr, nullptr, nullptr, nullptr, nullptr);
        ln_kernel<<<12608 / 4, 256, 0, stream>>>(tok, ybf, ln2_g + i * 768, ln2_b + i * 768, 12608, 768);
        gemm3<E_GELU><<<dim3(12, MT3), 512, G3_LDS, stream>>>(
            ybf, fc1T, 12608, 3072, 768, fc1_b + i * 3072, a1);
        gemm2<E_RESID><<<dim3(6, MT), 256, 0, stream>>>(
            a1, fc2T, 12608, 768, 3072,
            fc2_b + i * 768, nullptr, tok, nullptr, nullptr, nullptr, nullptr, nullptr);
    }

    // ---- final LN on cls rows, head weight transposes, MFMA projection head
    ln_kernel<<<16, 256, 0, stream>>>(tok, clsb, norm_g, norm_b, 64, 197 * 768);
    wtrans2<<<576, 256, 0, stream>>>(p1_w, p1T, 768, 768);
    wtrans2<<<384, 256, 0, stream>>>(p2_w, p2T, 768, 512);
    gemm2<E_HEAD1><<<dim3(6, 1), 256, 0, stream>>>(
        clsb, p1T, 64, 768, 768,
        nullptr, z1, nullptr, p1g, p1b, p1m, p1v, nullptr);
    gemm2<E_HEAD2><<<dim3(4, 1), 256, 0, stream>>>(
        z1, p2T, 64, 512, 768,
        nullptr, nullptr, (float*)d_out, p2g, p2b, p2m, p2v, nullptr);
}

// Round 14
// 4694.458 us; speedup vs baseline: 3.0109x; 3.0109x over previous
//
#include <hip/hip_runtime.h>
#include <hip/hip_bf16.h>

typedef __hip_bfloat16 bf16;
typedef __attribute__((ext_vector_type(8))) short bf16x8;
typedef __attribute__((ext_vector_type(4))) float f32x4;

__device__ __forceinline__ float bf2f(bf16 v) { return __bfloat162float(v); }
__device__ __forceinline__ unsigned short f2bfu(float f) {
    bf16 h = __float2bfloat16(f);
    return __builtin_bit_cast(unsigned short, h);
}

__device__ __forceinline__ void gload16(const void* g, void* lds) {
    __builtin_amdgcn_global_load_lds(
        (const __attribute__((address_space(1))) unsigned int*)g,
        (__attribute__((address_space(3))) unsigned int*)lds, 16, 0, 0);
}

// cheap exact-enough GELU: tanh form, max |err| vs erf-GELU ~5e-4
__device__ __forceinline__ float gelu_f(float x) {
    float u = 0.7978845608f * (x + 0.044715f * x * x * x);
    float e = __expf(-2.0f * fabsf(u));
    float th = (1.f - e) / (1.f + e);
    th = u < 0.f ? -th : th;
    return 0.5f * x * (1.f + th);
}

// ---------------------------------------------------------------- conv1 + ReLU + BN1
__global__ __launch_bounds__(256)
void conv1_kernel(const float* __restrict__ x, const float* __restrict__ w,
                  const float* __restrict__ bias,
                  const float* __restrict__ g, const float* __restrict__ b,
                  const float* __restrict__ m, const float* __restrict__ v,
                  bf16* __restrict__ h1) {
    int bo = blockIdx.x;
    int bb = bo >> 8, o = bo & 255;
    int l = threadIdx.x;
    if (l >= 200) return;
    const float* wo = w + o * 60;
    const float* xb = x + bb * 12000;
    float acc = bias[o];
#pragma unroll
    for (int i = 0; i < 12; i++)
#pragma unroll
        for (int t = 0; t < 5; t++)
            acc = fmaf(xb[i * 1000 + 5 * l + t], wo[i * 5 + t], acc);
    acc = fmaxf(acc, 0.f);
    float sc = g[o] * rsqrtf(v[o] + 1e-5f);
    acc = (acc - m[o]) * sc + b[o];
    h1[bo * 200 + l] = __float2bfloat16(acc);
}

// ---------------------------------------------------------------- im2col for conv2
__global__ __launch_bounds__(256)
void im2col_kernel(const bf16* __restrict__ h1, bf16* __restrict__ A2) {
    int idx = blockIdx.x * 256 + threadIdx.x;
    int row = idx / 1280, c = idx - row * 1280;
    int bb = row / 196, l = row - bb * 196;
    int i = c / 5, t = c - i * 5;
    A2[idx] = h1[(bb * 256 + i) * 200 + l + t];
}

// ---------------------------------------------------------------- cls token row
__global__ __launch_bounds__(256)
void add_cls_pos(const float* __restrict__ cls, const float* __restrict__ pos,
                 float* __restrict__ tok) {
    int idx = blockIdx.x * 256 + threadIdx.x;   // < 64*768
    int bb = idx / 768, d = idx - bb * 768;
    tok[(size_t)bb * 197 * 768 + d] = cls[d] + pos[d];
}

// ---------------------------------------------------------------- fp32 -> bf16 elementwise
__global__ __launch_bounds__(256)
void cvt_kernel(const float* __restrict__ in, bf16* __restrict__ out, int n) {
    int idx = blockIdx.x * 256 + threadIdx.x;
    if (idx < n) out[idx] = __float2bfloat16(in[idx]);
}

// ---------------------------------------------------------------- per-layer weight transpose+convert
__global__ __launch_bounds__(256)
void wtrans_layer(const float* __restrict__ qkvw, const float* __restrict__ projw,
                  const float* __restrict__ fc1w, const float* __restrict__ fc2w,
                  bf16* __restrict__ qkvT, bf16* __restrict__ projT,
                  bf16* __restrict__ fc1T, bf16* __restrict__ fc2T) {
    __shared__ float tile[32][33];
    int blk = blockIdx.x;
    const float* in; bf16* out; int Kd, Nd, t0;
    if (blk < 1728)      { in = qkvw; out = qkvT; Kd = 768;  Nd = 2304; t0 = blk; }
    else if (blk < 2304) { in = projw; out = projT; Kd = 768;  Nd = 768;  t0 = blk - 1728; }
    else if (blk < 4608) { in = fc1w; out = fc1T; Kd = 768;  Nd = 3072; t0 = blk - 2304; }
    else                 { in = fc2w; out = fc2T; Kd = 3072; Nd = 768;  t0 = blk - 4608; }
    int ntiles = Nd >> 5;
    int kt = t0 / ntiles, nt = t0 - kt * ntiles;
    int k0 = kt * 32, n0 = nt * 32;
    int tx = threadIdx.x & 31, ty = threadIdx.x >> 5;   // ty 0..7
#pragma unroll
    for (int j = 0; j < 4; j++)
        tile[ty + 8 * j][tx] = in[(size_t)(k0 + ty + 8 * j) * Nd + n0 + tx];
    __syncthreads();
#pragma unroll
    for (int j = 0; j < 4; j++)
        out[(size_t)(n0 + ty + 8 * j) * Kd + k0 + tx] = __float2bfloat16(tile[tx][ty + 8 * j]);
}

// ---------------------------------------------------------------- generic transpose+convert (head weights)
__global__ __launch_bounds__(256)
void wtrans2(const float* __restrict__ in, bf16* __restrict__ out, int Kd, int Nd) {
    __shared__ float tile[32][33];
    int ntiles = Nd >> 5;
    int kt = blockIdx.x / ntiles, nt = blockIdx.x - kt * ntiles;
    int k0 = kt * 32, n0 = nt * 32;
    int tx = threadIdx.x & 31, ty = threadIdx.x >> 5;
#pragma unroll
    for (int j = 0; j < 4; j++)
        tile[ty + 8 * j][tx] = in[(size_t)(k0 + ty + 8 * j) * Nd + n0 + tx];
    __syncthreads();
#pragma unroll
    for (int j = 0; j < 4; j++)
        out[(size_t)(n0 + ty + 8 * j) * Kd + k0 + tx] = __float2bfloat16(tile[tx][ty + 8 * j]);
}

// ---------------------------------------------------------------- LayerNorm (wave per row) -> bf16
__global__ __launch_bounds__(256)
void ln_kernel(const float* __restrict__ x, bf16* __restrict__ y,
               const float* __restrict__ g, const float* __restrict__ b,
               int nrows, int xstride) {
    int row = blockIdx.x * 4 + (threadIdx.x >> 6);
    if (row >= nrows) return;
    int l = threadIdx.x & 63;
    const float* xr = x + (size_t)row * xstride;
    float4 v0 = *(const float4*)(xr + l * 4);
    float4 v1 = *(const float4*)(xr + 256 + l * 4);
    float4 v2 = *(const float4*)(xr + 512 + l * 4);
    float s1 = 0.f, s2 = 0.f;
    {
        float e;
        e = v0.x; s1 += e; s2 += e * e;  e = v0.y; s1 += e; s2 += e * e;
        e = v0.z; s1 += e; s2 += e * e;  e = v0.w; s1 += e; s2 += e * e;
        e = v1.x; s1 += e; s2 += e * e;  e = v1.y; s1 += e; s2 += e * e;
        e = v1.z; s1 += e; s2 += e * e;  e = v1.w; s1 += e; s2 += e * e;
        e = v2.x; s1 += e; s2 += e * e;  e = v2.y; s1 += e; s2 += e * e;
        e = v2.z; s1 += e; s2 += e * e;  e = v2.w; s1 += e; s2 += e * e;
    }
#pragma unroll
    for (int off = 1; off < 64; off <<= 1) {
        s1 += __shfl_xor(s1, off);
        s2 += __shfl_xor(s2, off);
    }
    float mu = s1 * (1.f / 768.f);
    float rs = rsqrtf(s2 * (1.f / 768.f) - mu * mu + 1e-6f);
    bf16* yr = y + (size_t)row * 768;
#pragma unroll
    for (int sgi = 0; sgi < 3; sgi++) {
        float4 vv = sgi == 0 ? v0 : (sgi == 1 ? v1 : v2);
        float4 gg = *(const float4*)(g + sgi * 256 + l * 4);
        float4 bb = *(const float4*)(b + sgi * 256 + l * 4);
        ushort4 o;
        o.x = f2bfu((vv.x - mu) * rs * gg.x + bb.x);
        o.y = f2bfu((vv.y - mu) * rs * gg.y + bb.y);
        o.z = f2bfu((vv.z - mu) * rs * gg.z + bb.z);
        o.w = f2bfu((vv.w - mu) * rs * gg.w + bb.w);
        *(ushort4*)(yr + sgi * 256 + l * 4) = o;
    }
}

// ---------------------------------------------------------------- gemm2: 128x128, BK=64, 4 waves,
// single-buffer static LDS (R3/R6 proven) + XCD-chunked bijective swizzle (m204).
enum { E_BF16 = 0, E_RESID = 1, E_GELU = 2, E_CONV2 = 3, E_HEAD1 = 4, E_HEAD2 = 5 };

template<int EPI>
__global__ __launch_bounds__(256)
void gemm2(const bf16* __restrict__ A, const bf16* __restrict__ Bt,
           int M, int N, int K,
           const float* __restrict__ bias,
           bf16* __restrict__ Co, float* __restrict__ tok,
           const float* __restrict__ bng, const float* __restrict__ bnb,
           const float* __restrict__ bnm, const float* __restrict__ bnv,
           const float* __restrict__ pos) {
    __shared__ bf16 As[128 * 64];
    __shared__ bf16 Bs[128 * 64];
    const int t = threadIdx.x;
    const int l = t & 63, w = t >> 6;
    const int wm = (w >> 1) * 64, wn = (w & 1) * 64;

    const int gx = gridDim.x;
    const int nwg = gx * gridDim.y;
    const int d = blockIdx.y * gx + blockIdx.x;
    const int q = nwg >> 3, r = nwg & 7;
    const int xcd = d & 7, pos_ = d >> 3;
    const int lid = (xcd < r ? xcd * (q + 1) : r * (q + 1) + (xcd - r) * q) + pos_;
    const int row0 = (lid / gx) * 128, col0 = (lid % gx) * 128;

    const int lr = l & 15, kg = l >> 4;

    const int srow = w * 8 + (l >> 3);
    const int sc = ((l & 7) ^ (l >> 3)) * 8;
    const int dstoff = w * 1024 + l * 16;

    const f32x4 zero4 = {0.f, 0.f, 0.f, 0.f};
    f32x4 acc[4][4];
#pragma unroll
    for (int i = 0; i < 4; i++)
#pragma unroll
        for (int j = 0; j < 4; j++) acc[i][j] = zero4;

    for (int k0 = 0; k0 < K; k0 += 64) {
#pragma unroll
        for (int p = 0; p < 4; p++) {
            int rr = srow + p * 32;
            int gra = row0 + rr; if (gra >= M) gra = M - 1;
            gload16(A + (size_t)gra * K + k0 + sc, (char*)As + p * 4096 + dstoff);
            gload16(Bt + (size_t)(col0 + rr) * K + k0 + sc, (char*)Bs + p * 4096 + dstoff);
        }
        __syncthreads();
#pragma unroll
        for (int ks = 0; ks < 2; ks++) {
            bf16x8 af[4], bfv[4];
            const int cc = ((ks * 4 + kg) ^ (lr & 7)) * 16;
#pragma unroll
            for (int i = 0; i < 4; i++) {
                af[i]  = *(const bf16x8*)((const char*)As + (wm + i * 16 + lr) * 128 + cc);
                bfv[i] = *(const bf16x8*)((const char*)Bs + (wn + i * 16 + lr) * 128 + cc);
            }
#pragma unroll
            for (int i = 0; i < 4; i++)
#pragma unroll
                for (int j = 0; j < 4; j++)
                    acc[i][j] = __builtin_amdgcn_mfma_f32_16x16x32_bf16(af[i], bfv[j], acc[i][j], 0, 0, 0);
        }
        __syncthreads();
    }

    const int rbase = row0 + wm + (kg << 2);
#pragma unroll
    for (int i = 0; i < 4; i++) {
#pragma unroll
        for (int sr = 0; sr < 4; sr++) {
            int rr = rbase + i * 16 + sr;
            if (rr < M) {
#pragma unroll
                for (int j = 0; j < 4; j++) {
                    int c = col0 + wn + j * 16 + lr;
                    float vv = acc[i][j][sr];
                    if (EPI == E_BF16) {
                        Co[(size_t)rr * N + c] = __float2bfloat16(vv);
                    } else if (EPI == E_RESID) {
                        float* p = tok + (size_t)rr * N + c;
                        *p += vv + bias[c];
                    } else if (EPI == E_GELU) {
                        Co[(size_t)rr * N + c] = __float2bfloat16(gelu_f(vv + bias[c]));
                    } else if (EPI == E_CONV2) {
                        float xx = vv + bias[c];
                        xx = fmaxf(xx, 0.f);
                        float sc2 = bng[c] * rsqrtf(bnv[c] + 1e-5f);
                        xx = (xx - bnm[c]) * sc2 + bnb[c];
                        int bb = rr / 196, ll = rr - bb * 196;
                        xx += pos[(size_t)(1 + ll) * 768 + c];
                        tok[(size_t)(bb * 197 + 1 + ll) * 768 + c] = xx;
                    } else if (EPI == E_HEAD1) {
                        float sc2 = bng[c] * rsqrtf(bnv[c] + 1e-5f);
                        float xx = (vv - bnm[c]) * sc2 + bnb[c];
                        xx = fmaxf(xx, 0.f);
                        Co[(size_t)rr * N + c] = __float2bfloat16(xx);
                    } else {
                        float sc2 = bng[c] * rsqrtf(bnv[c] + 1e-5f);
                        tok[(size_t)rr * N + c] = (vv - bnm[c]) * sc2 + bnb[c];
                    }
                }
            }
        }
    }
}

// ---------------------------------------------------------------- gemm3: 256x256 tile, 8 waves, BK=32,
// 2-buffer double-buffered LDS (64 KB), stage(j+1) -> compute(j) -> vmcnt(0)+barrier.
// Conflict-free swizzle: phys_chunk = logical ^ ((row>>1)&3). __launch_bounds__(512,2):
// R13 proved (512,4) forces VGPR<=64 and spills the 128-reg accumulator (722us/dispatch).
#define G3_LDS 65536

template<int EPI>
__global__ __launch_bounds__(512, 2)
void gemm3(const bf16* __restrict__ A, const bf16* __restrict__ Bt,
           int M, int N, int K,
           const float* __restrict__ bias, bf16* __restrict__ Co) {
    extern __shared__ char smem[];   // 2 bufs x { A 16K | B 16K }
    const int t = threadIdx.x;
    const int l = t & 63, wid = t >> 6;
    const int wr = wid >> 2, wc = wid & 3;          // wave -> (row half, col quarter)
    const int lr = l & 15, kg = l >> 4;

    // XCD-chunked bijective swizzle (m204)
    const int gx = gridDim.x;
    const int nwg = gx * gridDim.y;
    const int d = blockIdx.y * gx + blockIdx.x;
    const int q = nwg >> 3, r = nwg & 7;
    const int xcd = d & 7, pp = d >> 3;
    const int lid = (xcd < r ? xcd * (q + 1) : r * (q + 1) + (xcd - r) * q) + pp;
    const int row0 = (lid / gx) * 256, col0 = (lid % gx) * 256;

    // staging: thread t covers rows (t>>2) and 128+(t>>2), phys chunk (t&3);
    // source logical chunk = (t&3) ^ ((row>>1)&3) = (t&3) ^ ((t>>3)&3)
    const int srow = t >> 2;                          // 0..127
    const int clog = ((t & 3) ^ ((t >> 3) & 3)) * 8;  // element offset of logical chunk
    int ga0 = row0 + srow;        if (ga0 >= M) ga0 = M - 1;
    int ga1 = row0 + 128 + srow;  if (ga1 >= M) ga1 = M - 1;
    const bf16* Ap0 = A + (size_t)ga0 * K + clog;
    const bf16* Ap1 = A + (size_t)ga1 * K + clog;
    const bf16* Bp0 = Bt + (size_t)(col0 + srow) * K + clog;
    const bf16* Bp1 = Bt + (size_t)(col0 + 128 + srow) * K + clog;
    const int dst = t * 16;

    const f32x4 zero4 = {0.f, 0.f, 0.f, 0.f};
    f32x4 acc[8][4];
#pragma unroll
    for (int i = 0; i < 8; i++)
#pragma unroll
        for (int n = 0; n < 4; n++) acc[i][n] = zero4;

    auto stage = [&](int j) {
        char* base = smem + (j & 1) * 32768 + dst;
        const int ke = j * 32;
        gload16(Ap0 + ke, base);
        gload16(Ap1 + ke, base + 8192);
        gload16(Bp0 + ke, base + 16384);
        gload16(Bp1 + ke, base + 16384 + 8192);
    };

    // read addressing: row R at byte R*64, phys chunk = kg ^ ((R>>1)&3); (R>>1)&3 == (lr>>1)&3
    const int ccA = ((kg ^ ((lr >> 1) & 3)) * 16);
    const int arow = (wr * 128 + lr) * 64 + ccA;       // + i*16*64
    const int brow = (wc * 64 + lr) * 64 + ccA;        // + n*16*64, +16384

    auto compute = [&](int j) {
        const char* ab = smem + (j & 1) * 32768;
        bf16x8 bfrag[4];
#pragma unroll
        for (int n = 0; n < 4; n++)
            bfrag[n] = *(const bf16x8*)(ab + 16384 + brow + n * 1024);
#pragma unroll
        for (int mh = 0; mh < 2; mh++) {
            bf16x8 af[4];
#pragma unroll
            for (int i2 = 0; i2 < 4; i2++)
                af[i2] = *(const bf16x8*)(ab + arow + (mh * 4 + i2) * 1024);
            __builtin_amdgcn_s_setprio(1);
#pragma unroll
            for (int i2 = 0; i2 < 4; i2++)
#pragma unroll
                for (int n = 0; n < 4; n++)
                    acc[mh * 4 + i2][n] = __builtin_amdgcn_mfma_f32_16x16x32_bf16(
                        af[i2], bfrag[n], acc[mh * 4 + i2][n], 0, 0, 0);
            __builtin_amdgcn_s_setprio(0);
        }
    };

    const int nt = K >> 5;
    stage(0);
    asm volatile("s_waitcnt vmcnt(0)" ::: "memory");
    __syncthreads();

    for (int j = 0; j < nt; ++j) {
        if (j + 1 < nt) stage(j + 1);      // -> buf (j+1)&1, disjoint from compute's buf j&1
        compute(j);
        asm volatile("s_waitcnt vmcnt(0)" ::: "memory");   // stage(j+1) landed
        __syncthreads();                   // all waves done reading buf j&1 -> safe to overwrite next iter
    }

    // epilogue: row = row0 + wr*128 + i*16 + kg*4 + sr; col = col0 + wc*64 + n*16 + lr
    float bs[4];
#pragma unroll
    for (int n = 0; n < 4; n++)
        bs[n] = (EPI == E_GELU) ? bias[col0 + wc * 64 + n * 16 + lr] : 0.f;
    const int rb = row0 + wr * 128 + kg * 4;
    const int cb = col0 + wc * 64 + lr;
#pragma unroll
    for (int i = 0; i < 8; i++) {
#pragma unroll
        for (int sr = 0; sr < 4; sr++) {
            int rr = rb + i * 16 + sr;
            if (rr < M) {
#pragma unroll
                for (int n = 0; n < 4; n++) {
                    float vv = acc[i][n][sr];
                    if (EPI == E_GELU) vv = gelu_f(vv + bs[n]);
                    Co[(size_t)rr * N + cb + n * 16] = __float2bfloat16(vv);
                }
            }
        }
    }
}

// ---------------------------------------------------------------- fused attention, 1 block per (b,h)
#define ATTN_LDS (208 * 72 * 2 + 64 * 232 * 2 + 4 * 16 * 232 * 2)

__global__ __launch_bounds__(256)
void attn_kernel(const bf16* __restrict__ qkv, bf16* __restrict__ o) {
    extern __shared__ char smem[];
    bf16* Ks = (bf16*)smem;          // [208][72]
    bf16* Vt = Ks + 208 * 72;        // [64][232]
    bf16* Pl = Vt + 64 * 232;        // [4][16][232]
    const int bh = blockIdx.x, bb = bh / 12, h = bh - bb * 12;
    const int t = threadIdx.x, w = t >> 6, l = t & 63;
    const int lr = l & 15, lk8 = (l >> 4) * 8;
    const size_t base = (size_t)bb * 197 * 2304 + (size_t)h * 64;

    for (int qi = t; qi < 197 * 16; qi += 256) {   // K rows
        int n = qi >> 4, d4 = (qi & 15) << 2;
        ushort4 kv = *(const ushort4*)(qkv + base + (size_t)n * 2304 + 768 + d4);
        *(ushort4*)&Ks[n * 72 + d4] = kv;
    }
    for (int qi = t; qi < 11 * 72; qi += 256) ((unsigned short*)Ks)[197 * 72 + qi] = 0;
    for (int qi = t; qi < 197 * 16; qi += 256) {   // V transposed
        int n = qi >> 4, d4 = (qi & 15) << 2;
        ushort4 vv = *(const ushort4*)(qkv + base + (size_t)n * 2304 + 1536 + d4);
        ((unsigned short*)Vt)[(d4 + 0) * 232 + n] = vv.x;
        ((unsigned short*)Vt)[(d4 + 1) * 232 + n] = vv.y;
        ((unsigned short*)Vt)[(d4 + 2) * 232 + n] = vv.z;
        ((unsigned short*)Vt)[(d4 + 3) * 232 + n] = vv.w;
    }
    for (int qi = t; qi < 64 * 35; qi += 256) {
        int d = qi / 35, c = 197 + (qi - d * 35);
        ((unsigned short*)Vt)[d * 232 + c] = 0;
    }
    __syncthreads();

    bf16* Pw = Pl + w * (16 * 232);
    const f32x4 zero4 = {0.f, 0.f, 0.f, 0.f};
    for (int qt = w; qt < 13; qt += 4) {
        int m0 = qt * 16;
        int qrow = m0 + lr; if (qrow > 196) qrow = 196;
        const bf16* qp = qkv + (size_t)(bb * 197 + qrow) * 2304 + h * 64 + lk8;
        bf16x8 a0 = *(const bf16x8*)qp;
        bf16x8 a1 = *(const bf16x8*)(qp + 32);
        f32x4 s[13];
#pragma unroll
        for (int kt = 0; kt < 13; kt++) {
            const bf16* kp = &Ks[(kt * 16 + lr) * 72 + lk8];
            bf16x8 b0 = *(const bf16x8*)kp;
            bf16x8 b1 = *(const bf16x8*)(kp + 32);
            f32x4 z = zero4;
            z = __builtin_amdgcn_mfma_f32_16x16x32_bf16(a0, b0, z, 0, 0, 0);
            z = __builtin_amdgcn_mfma_f32_16x16x32_bf16(a1, b1, z, 0, 0, 0);
            s[kt] = z;
        }
        float mx[4] = {-1e30f, -1e30f, -1e30f, -1e30f};
#pragma unroll
        for (int kt = 0; kt < 13; kt++) {
            bool valid = (kt < 12) || (lr <= 4);    // col = kt*16+lr <= 196
#pragma unroll
            for (int sr = 0; sr < 4; sr++) {
                float sv = s[kt][sr] * 0.125f;
                sv = valid ? sv : -1e30f;
                s[kt][sr] = sv;
                mx[sr] = fmaxf(mx[sr], sv);
            }
        }
#pragma unroll
        for (int off = 1; off < 16; off <<= 1)
#pragma unroll
            for (int sr = 0; sr < 4; sr++)
                mx[sr] = fmaxf(mx[sr], __shfl_xor(mx[sr], off));
        float sum[4] = {0.f, 0.f, 0.f, 0.f};
#pragma unroll
        for (int kt = 0; kt < 13; kt++)
#pragma unroll
            for (int sr = 0; sr < 4; sr++) {
                float p = __expf(s[kt][sr] - mx[sr]);
                s[kt][sr] = p;
                sum[sr] += p;
            }
#pragma unroll
        for (int off = 1; off < 16; off <<= 1)
#pragma unroll
            for (int sr = 0; sr < 4; sr++)
                sum[sr] += __shfl_xor(sum[sr], off);
        float inv[4];
#pragma unroll
        for (int sr = 0; sr < 4; sr++) inv[sr] = 1.f / sum[sr];
#pragma unroll
        for (int kt = 0; kt < 13; kt++)
#pragma unroll
            for (int sr = 0; sr < 4; sr++)
                ((unsigned short*)Pw)[((l >> 4) * 4 + sr) * 232 + kt * 16 + lr] =
                    f2bfu(s[kt][sr] * inv[sr]);
        for (int j = l; j < 256; j += 64) {        // zero P cols 208..223
            int rr = j >> 4, cc = 208 + (j & 15);
            ((unsigned short*)Pw)[rr * 232 + cc] = 0;
        }
        asm volatile("s_waitcnt lgkmcnt(0)" ::: "memory");
        f32x4 oa[4];
#pragma unroll
        for (int nf = 0; nf < 4; nf++) oa[nf] = zero4;
#pragma unroll
        for (int ks = 0; ks < 7; ks++) {
            const bf16* pp = &Pw[lr * 232 + ks * 32 + lk8];
            bf16x8 ap = *(const bf16x8*)pp;
#pragma unroll
            for (int nf = 0; nf < 4; nf++) {
                bf16x8 bv = *(const bf16x8*)&Vt[(nf * 16 + lr) * 232 + ks * 32 + lk8];
                oa[nf] = __builtin_amdgcn_mfma_f32_16x16x32_bf16(ap, bv, oa[nf], 0, 0, 0);
            }
        }
#pragma unroll
        for (int nf = 0; nf < 4; nf++)
#pragma unroll
            for (int sr = 0; sr < 4; sr++) {
                int orow = m0 + (l >> 4) * 4 + sr;
                if (orow <= 196)
                    o[(size_t)(bb * 197 + orow) * 768 + h * 64 + nf * 16 + lr] =
                        __float2bfloat16(oa[nf][sr]);
            }
    }
}

// ================================================================ host
extern "C" void kernel_launch(void* const* d_in, const int* in_sizes, int n_in,
                              void* d_out, int out_size, void* d_ws, size_t ws_size,
                              hipStream_t stream) {
    (void)in_sizes; (void)n_in; (void)out_size; (void)ws_size;
    const float* x        = (const float*)d_in[0];
    const float* conv1_w  = (const float*)d_in[1];
    const float* conv1_b  = (const float*)d_in[2];
    const float* bn1_g = (const float*)d_in[3],  *bn1_b = (const float*)d_in[4];
    const float* bn1_m = (const float*)d_in[5],  *bn1_v = (const float*)d_in[6];
    const float* conv2_w  = (const float*)d_in[7];
    const float* conv2_b  = (const float*)d_in[8];
    const float* bn2_g = (const float*)d_in[9],  *bn2_b = (const float*)d_in[10];
    const float* bn2_m = (const float*)d_in[11], *bn2_v = (const float*)d_in[12];
    const float* cls_tok  = (const float*)d_in[13];
    const float* pos      = (const float*)d_in[14];
    const float* ln1_g = (const float*)d_in[15], *ln1_b = (const float*)d_in[16];
    const float* qkv_w = (const float*)d_in[17];
    const float* proj_w = (const float*)d_in[18], *proj_b = (const float*)d_in[19];
    const float* ln2_g = (const float*)d_in[20], *ln2_b = (const float*)d_in[21];
    const float* fc1_w = (const float*)d_in[22], *fc1_b = (const float*)d_in[23];
    const float* fc2_w = (const float*)d_in[24], *fc2_b = (const float*)d_in[25];
    const float* norm_g = (const float*)d_in[26], *norm_b = (const float*)d_in[27];
    const float* p1_w = (const float*)d_in[28];
    const float* p1g = (const float*)d_in[29], *p1b = (const float*)d_in[30];
    const float* p1m = (const float*)d_in[31], *p1v = (const float*)d_in[32];
    const float* p2_w = (const float*)d_in[33];
    const float* p2g = (const float*)d_in[34], *p2b = (const float*)d_in[35];
    const float* p2m = (const float*)d_in[36], *p2v = (const float*)d_in[37];

    char* ws = (char*)d_ws;
    float* tok  = (float*)(ws + 0);                        // 38,731,776 B
    bf16* ybf   = (bf16*)(ws + 38731776);                  // 19,365,888 B (LN out / attn out)
    bf16* qkvb  = (bf16*)(ws + 58097664);                  // 58,097,664 B
    bf16* a1    = (bf16*)(ws + 116195328);                 // 77,463,552 B (GELU act)
    bf16* h1    = (bf16*)(ws + 116195328);                 // alias (prologue only)
    bf16* A2    = (bf16*)(ws + 116195328 + 8388608);       // alias (prologue only)
    bf16* clsb  = (bf16*)(ws + 193658880);                 // 98,304 B
    bf16* z1    = (bf16*)(ws + 193757184);                 // 98,304 B
    bf16* wtb   = (bf16*)(ws + 193953792);                 // 14,155,776 B (per-layer bf16 weights)
    bf16* qkvT = wtb;                                      // [2304][768]
    bf16* projT = wtb + 1769472;                           // [768][768]
    bf16* fc1T = wtb + 2359296;                            // [3072][768]
    bf16* fc2T = wtb + 4718592;                            // [768][3072]
    bf16* conv2T = wtb;                                    // prologue alias [768][1280]
    bf16* p1T = a1;                                        // epilogue alias [768][768]
    bf16* p2T = a1 + 768 * 768;                            // epilogue alias [512][768]

    (void)hipFuncSetAttribute((const void*)attn_kernel,
                              hipFuncAttributeMaxDynamicSharedMemorySize, ATTN_LDS);
    (void)hipFuncSetAttribute((const void*)gemm3<E_BF16>,
                              hipFuncAttributeMaxDynamicSharedMemorySize, G3_LDS);
    (void)hipFuncSetAttribute((const void*)gemm3<E_GELU>,
                              hipFuncAttributeMaxDynamicSharedMemorySize, G3_LDS);

    // ---- patch embed
    conv1_kernel<<<64 * 256, 256, 0, stream>>>(x, conv1_w, conv1_b, bn1_g, bn1_b, bn1_m, bn1_v, h1);
    im2col_kernel<<<(12544 * 1280) / 256, 256, 0, stream>>>(h1, A2);
    cvt_kernel<<<(768 * 1280 + 255) / 256, 256, 0, stream>>>(conv2_w, conv2T, 768 * 1280);
    gemm2<E_CONV2><<<dim3(6, 98), 256, 0, stream>>>(
        A2, conv2T, 12544, 768, 1280, conv2_b, nullptr, tok, bn2_g, bn2_b, bn2_m, bn2_v, pos);
    add_cls_pos<<<(64 * 768) / 256, 256, 0, stream>>>(cls_tok, pos, tok);

    const int MT = (12608 + 127) / 128;  // 99
    const int MT3 = (12608 + 255) / 256; // 50
    for (int i = 0; i < 12; i++) {
        wtrans_layer<<<6912, 256, 0, stream>>>(
            qkv_w + (size_t)i * 768 * 2304, proj_w + (size_t)i * 768 * 768,
            fc1_w + (size_t)i * 768 * 3072, fc2_w + (size_t)i * 3072 * 768,
            qkvT, projT, fc1T, fc2T);
        ln_kernel<<<12608 / 4, 256, 0, stream>>>(tok, ybf, ln1_g + i * 768, ln1_b + i * 768, 12608, 768);
        gemm3<E_BF16><<<dim3(9, MT3), 512, G3_LDS, stream>>>(
            ybf, qkvT, 12608, 2304, 768, nullptr, qkvb);
        attn_kernel<<<768, 256, ATTN_LDS, stream>>>(qkvb, ybf);
        gemm2<E_RESID><<<dim3(6, MT), 256, 0, stream>>>(
            ybf, projT, 12608, 768, 768,
            proj_b + i * 768, nullptr, tok, nullptr, nullptr, nullptr, nullptr, nullptr);
        ln_kernel<<<12608 / 4, 256, 0, stream>>>(tok, ybf, ln2_g + i * 768, ln2_b + i * 768, 12608, 768);
        gemm3<E_GELU><<<dim3(12, MT3), 512, G3_LDS, stream>>>(
            ybf, fc1T, 12608, 3072, 768, fc1_b + i * 3072, a1);
        gemm2<E_RESID><<<dim3(6, MT), 256, 0, stream>>>(
            a1, fc2T, 12608, 768, 3072,
            fc2_b + i * 768, nullptr, tok, nullptr, nullptr, nullptr, nullptr, nullptr);
    }

    // ---- final LN on cls rows, head weight transposes, MFMA projection head
    ln_kernel<<<16, 256, 0, stream>>>(tok, clsb, norm_g, norm_b, 64, 197 * 768);
    wtrans2<<<576, 256, 0, stream>>>(p1_w, p1T, 768, 768);
    wtrans2<<<384, 256, 0, stream>>>(p2_w, p2T, 768, 512);
    gemm2<E_HEAD1><<<dim3(6, 1), 256, 0, stream>>>(
        clsb, p1T, 64, 768, 768,
        nullptr, z1, nullptr, p1g, p1b, p1m, p1v, nullptr);
    gemm2<E_HEAD2><<<dim3(4, 1), 256, 0, stream>>>(
        z1, p2T, 64, 512, 768,
        nullptr, nullptr, (float*)d_out, p2g, p2b, p2m, p2v, nullptr);
}